// Round 4
// baseline (17.489 us; speedup 1.0000x reference)
//
#include <hip/hip_runtime.h>
#include <hip/hip_bf16.h>

// FastTextItout, MFMA + prepacked-W + L1-resident bf16 emb.
// out[b] = sum_h relu( xw[b,:] @ W[:,h] + S*(lif_b[h]+beta) ) * fc_w[h] + fc_b
// xw[b,:] = sum_t alpha^(63-t) * emb[xis[b,t],:],  S = sum_{k<64} alpha^k.
// B=16384, T=64, EMB=16 (K padded to 32), HID=1024, VOCAB=1001.
//
// d_ws layout (bytes):
//   0      : wpack  64 htiles x 64 lanes x 16B bf16 fragments   (65536)
//   65536  : wbias  1024 f32  = S*(lif_b+beta)                  (4096)
//   69632  : wfcw   1024 f32  = fc_w                            (4096)
//   73728  : embb   1001*16 bf16 emb table (31.3 KB, L1-fits)   (32032)

#define BB    16384
#define TT    64
#define EMBD  16
#define HIDD  1024
#define NVOC  1001
#define ROWS  32
#define NTHR  512
#define NBLK  (BB / ROWS)     // 512 blocks -> 2 blocks/CU
#define XWPAD 24
#define HTPW  8

#define WS_WBIAS 65536
#define WS_WFCW  69632
#define WS_EMBB  73728

typedef __attribute__((ext_vector_type(8))) short          frag_ab;
typedef __attribute__((ext_vector_type(4))) float          frag_cd;
typedef __attribute__((ext_vector_type(4))) unsigned short us4;

__device__ __forceinline__ float bf2f(unsigned short u) {
    union { unsigned int i; float f; } x; x.i = ((unsigned int)u) << 16; return x.f;
}
__device__ __forceinline__ unsigned short f2b(float f) {
    __hip_bfloat16 h = __float2bfloat16(f);   // RNE
    return __builtin_bit_cast(unsigned short, h);
}

// ---------------- prep: pack W fragments, bias, fcw, bf16 emb ----------------
__global__ __launch_bounds__(256)
void ftt_prep(const float* __restrict__ emb, const float* __restrict__ lif_w,
              const float* __restrict__ lif_b, const float* __restrict__ fc_w,
              const float* __restrict__ alpha_p, const float* __restrict__ beta_p,
              void* __restrict__ ws)
{
    const int s = blockIdx.x * 256 + threadIdx.x;
    uint4* wpack          = (uint4*)ws;
    float* wbias          = (float*)((char*)ws + WS_WBIAS);
    float* wfcw           = (float*)((char*)ws + WS_WFCW);
    unsigned short* embb  = (unsigned short*)((char*)ws + WS_EMBB);

    if (s < 4096) {
        // one MFMA B-fragment per thread: htile j2, lane l=(kg,nn)
        const int j2 = s >> 6;
        const int l  = s & 63;
        const int kg = l >> 4;
        const int nn = l & 15;
        uint4 u = {0u, 0u, 0u, 0u};
        if (kg < 2) {
            unsigned int t[8];
            #pragma unroll
            for (int i = 0; i < 8; ++i)
                t[i] = (unsigned int)f2b(lif_w[(kg * 8 + i) * HIDD + j2 * 16 + nn]);
            u.x = t[0] | (t[1] << 16);
            u.y = t[2] | (t[3] << 16);
            u.z = t[4] | (t[5] << 16);
            u.w = t[6] | (t[7] << 16);
        }
        wpack[s] = u;
    } else if (s < 4096 + 4004) {
        // bf16 emb table: one e-quad per thread
        const int e = s - 4096;
        const int v = e >> 2, q = e & 3;
        const float4 f = *(const float4*)(emb + (size_t)v * EMBD + q * 4);
        us4 u = { f2b(f.x), f2b(f.y), f2b(f.z), f2b(f.w) };
        *(us4*)&embb[v * EMBD + q * 4] = u;
    } else if (s >= 8192 && s < 8192 + HIDD) {
        const int h = s - 8192;
        const float alpha = alpha_p[0];
        const float a2 = alpha * alpha, a4 = a2 * a2, a8 = a4 * a4;
        const float a16 = a8 * a8, a32 = a16 * a16, a64 = a32 * a32;
        const float S = (fabsf(1.f - alpha) < 1e-8f) ? (float)TT
                                                     : (1.f - a64) / (1.f - alpha);
        wbias[h] = S * (lif_b[h] + beta_p[0]);
        wfcw[h]  = fc_w[h];
    }
}

// ---------------- main ----------------
__global__ __launch_bounds__(NTHR, 4)
void ftt_kernel(const int* __restrict__ xis, const float* __restrict__ fc_b,
                const float* __restrict__ alpha_p, const void* __restrict__ ws,
                float* __restrict__ out)
{
    __shared__ unsigned short xwb[ROWS * XWPAD];    // bf16 XW tile
    __shared__ float red[ROWS / 16][8][16];         // per-wave partials

    const uint4* wpack           = (const uint4*)ws;
    const float* wbias           = (const float*)((const char*)ws + WS_WBIAS);
    const float* wfcw            = (const float*)((const char*)ws + WS_WFCW);
    const unsigned short* embb   = (const unsigned short*)((const char*)ws + WS_EMBB);

    const int tid  = threadIdx.x;
    const int lane = tid & 63;
    const int wave = tid >> 6;
    const int row0 = blockIdx.x * ROWS;
    const float alpha = alpha_p[0];

    const float a2  = alpha * alpha;
    const float a4  = a2 * a2;
    const float a8  = a4 * a4;
    const float a16 = a8 * a8;
    const float a32 = a16 * a16;
    const float a48 = a32 * a16;

    const int nn = lane & 15;   // MFMA col within tile
    const int kg = lane >> 4;   // k-group

    // ---- W fragments / bias / fcw: fully coalesced from ws
    frag_ab bfrag[HTPW];
    float   biasr[HTPW], fcwr[HTPW];
    #pragma unroll
    for (int j = 0; j < HTPW; ++j) {
        const int j2 = wave * HTPW + j;
        bfrag[j] = __builtin_bit_cast(frag_ab, wpack[j2 * 64 + lane]);
        const int h = j2 * 16 + nn;
        biasr[j] = wbias[h];
        fcwr[j]  = wfcw[h];
    }

    // ---- gather: xw[r][:] = sum_t alpha^(63-t) * emb[xis[r][t]][:]
    // 16 threads/row: c = t-chunk (16 t), q = e-quad (4 elems), bf16 L1-hit reads.
    {
        const int r   = tid >> 4;
        const int sub = tid & 15;
        const int c   = sub >> 2;
        const int q   = sub & 3;
        const int4* xp = (const int4*)(xis + (size_t)(row0 + r) * TT + c * 16);
        const unsigned short* eb = embb + q * 4;
        float ax = 0.f, ay = 0.f, az = 0.f, aw = 0.f;
        float w = 1.f;
        #pragma unroll
        for (int cc = 3; cc >= 0; --cc) {
            const int4 iv = xp[cc];
            { const us4 e = *(const us4*)(eb + ((size_t)iv.w << 4));
              ax += w * bf2f(e.x); ay += w * bf2f(e.y);
              az += w * bf2f(e.z); aw += w * bf2f(e.w); w *= alpha; }
            { const us4 e = *(const us4*)(eb + ((size_t)iv.z << 4));
              ax += w * bf2f(e.x); ay += w * bf2f(e.y);
              az += w * bf2f(e.z); aw += w * bf2f(e.w); w *= alpha; }
            { const us4 e = *(const us4*)(eb + ((size_t)iv.y << 4));
              ax += w * bf2f(e.x); ay += w * bf2f(e.y);
              az += w * bf2f(e.z); aw += w * bf2f(e.w); w *= alpha; }
            { const us4 e = *(const us4*)(eb + ((size_t)iv.x << 4));
              ax += w * bf2f(e.x); ay += w * bf2f(e.y);
              az += w * bf2f(e.z); aw += w * bf2f(e.w); w *= alpha; }
        }
        const float sc = (c == 3) ? 1.f : ((c == 2) ? a16 : ((c == 1) ? a32 : a48));
        ax *= sc; ay *= sc; az *= sc; aw *= sc;
        ax += __shfl_xor(ax, 4); ay += __shfl_xor(ay, 4);
        az += __shfl_xor(az, 4); aw += __shfl_xor(aw, 4);
        ax += __shfl_xor(ax, 8); ay += __shfl_xor(ay, 8);
        az += __shfl_xor(az, 8); aw += __shfl_xor(aw, 8);
        if (c == 0) {
            us4 u = { f2b(ax), f2b(ay), f2b(az), f2b(aw) };
            *(us4*)&xwb[r * XWPAD + q * 4] = u;
        }
    }
    __syncthreads();   // xwb ready

    // ---- MFMA: 2 row-tiles x 8 h-tiles per wave, fused relu-dot epilogue
    #pragma unroll
    for (int rt = 0; rt < ROWS / 16; ++rt) {
        frag_ab a = {0, 0, 0, 0, 0, 0, 0, 0};
        if (kg < 2)
            a = *(const frag_ab*)&xwb[(rt * 16 + nn) * XWPAD + kg * 8];
        frag_cd pacc = {0.f, 0.f, 0.f, 0.f};
        #pragma unroll
        for (int j = 0; j < HTPW; ++j) {
            frag_cd z = { biasr[j], biasr[j], biasr[j], biasr[j] };
            frag_cd c = __builtin_amdgcn_mfma_f32_16x16x32_bf16(a, bfrag[j], z, 0, 0, 0);
            #pragma unroll
            for (int x = 0; x < 4; ++x)
                pacc[x] += fmaxf(c[x], 0.f) * fcwr[j];
        }
        #pragma unroll
        for (int m = 1; m <= 8; m <<= 1) {
            #pragma unroll
            for (int x = 0; x < 4; ++x) pacc[x] += __shfl_xor(pacc[x], m);
        }
        if (nn == 0) {
            #pragma unroll
            for (int x = 0; x < 4; ++x)
                red[rt][wave][kg * 4 + x] = pacc[x];
        }
    }
    __syncthreads();

    if (tid < ROWS) {
        float s = fc_b[0];
        #pragma unroll
        for (int w2 = 0; w2 < 8; ++w2) s += red[tid >> 4][w2][tid & 15];
        out[row0 + tid] = s;
    }
}

extern "C" void kernel_launch(void* const* d_in, const int* in_sizes, int n_in,
                              void* d_out, int out_size, void* d_ws, size_t ws_size,
                              hipStream_t stream) {
    const int*   xis   = (const int*)d_in[0];
    const float* emb   = (const float*)d_in[1];
    const float* lif_w = (const float*)d_in[2];
    const float* lif_b = (const float*)d_in[3];
    const float* fc_w  = (const float*)d_in[4];
    const float* fc_b  = (const float*)d_in[5];
    const float* alpha = (const float*)d_in[6];
    const float* beta  = (const float*)d_in[7];
    float* out = (float*)d_out;

    ftt_prep<<<36, 256, 0, stream>>>(emb, lif_w, lif_b, fc_w, alpha, beta, d_ws);
    ftt_kernel<<<NBLK, NTHR, 0, stream>>>(xis, fc_b, alpha, d_ws, out);
}

// Round 5
// 14.552 us; speedup vs baseline: 1.2018x; 1.2018x over previous
//
#include <hip/hip_runtime.h>
#include <hip/hip_bf16.h>

// FastTextItout, single-launch: LDS bf16 emb + cooperative (broadcast) gather
// + MFMA epilogue.
// out[b] = sum_h relu( xw[b,:] @ W[:,h] + S*(lif_b[h]+beta) ) * fc_w[h] + fc_b
// xw[b,:] = sum_t alpha^(63-t) * emb[xis[b,t],:],  S = sum_{k<64} alpha^k.
// B=16384, T=64, EMB=16 (K padded to 32), HID=1024, VOCAB=1001.

#define BB    16384
#define TT    64
#define EMBD  16
#define HIDD  1024
#define NVOC  1001
#define ROWS  32
#define NTHR  512
#define NBLK  (BB / ROWS)     // 512 blocks -> 2 blocks/CU
#define XWPAD 24
#define HTPW  8

typedef __attribute__((ext_vector_type(8))) short          frag_ab;
typedef __attribute__((ext_vector_type(4))) float          frag_cd;
typedef __attribute__((ext_vector_type(4))) unsigned short us4;

__device__ __forceinline__ float bf2f(unsigned short u) {
    union { unsigned int i; float f; } x; x.i = ((unsigned int)u) << 16; return x.f;
}
__device__ __forceinline__ unsigned short f2b(float f) {
    __hip_bfloat16 h = __float2bfloat16(f);   // RNE
    return __builtin_bit_cast(unsigned short, h);
}

__global__ __launch_bounds__(NTHR, 4)   // 4 waves/EU -> 2 blocks/CU
void ftt_kernel(const int* __restrict__ xis, const float* __restrict__ emb,
                const float* __restrict__ lif_w, const float* __restrict__ lif_b,
                const float* __restrict__ fc_w, const float* __restrict__ fc_b,
                const float* __restrict__ alpha_p, const float* __restrict__ beta_p,
                float* __restrict__ out)
{
    __shared__ unsigned short embl[NVOC * EMBD];    // 32032 B bf16 emb (unpadded:
                                                    // 4-lane groups read consecutive
                                                    // quads -> banks spread by design)
    __shared__ unsigned short xwb[ROWS * XWPAD];    // 1536 B bf16 XW tile
    __shared__ float red[ROWS / 16][8][16];         // 2 KB per-wave partials

    const int tid  = threadIdx.x;
    const int lane = tid & 63;
    const int wave = tid >> 6;
    const int row0 = blockIdx.x * ROWS;
    const float alpha = alpha_p[0];
    const float beta  = beta_p[0];

    // alpha powers + geometric sum
    const float a2  = alpha * alpha;
    const float a4  = a2 * a2;
    const float a8  = a4 * a4;
    const float a16 = a8 * a8;
    const float a32 = a16 * a16;
    const float a48 = a32 * a16;
    const float a64 = a32 * a32;
    const float S   = (fabsf(1.f - alpha) < 1e-8f) ? (float)TT
                                                   : (1.f - a64) / (1.f - alpha);

    // ---- stage emb f32 -> bf16 into LDS (coalesced: 1 row / thread)
    for (int v = tid; v < NVOC; v += NTHR) {
        const float4* ep = (const float4*)(emb + (size_t)v * EMBD);
        const float4 e0 = ep[0], e1 = ep[1], e2 = ep[2], e3 = ep[3];
        us4 u0 = { f2b(e0.x), f2b(e0.y), f2b(e0.z), f2b(e0.w) };
        us4 u1 = { f2b(e1.x), f2b(e1.y), f2b(e1.z), f2b(e1.w) };
        us4 u2 = { f2b(e2.x), f2b(e2.y), f2b(e2.z), f2b(e2.w) };
        us4 u3 = { f2b(e3.x), f2b(e3.y), f2b(e3.z), f2b(e3.w) };
        *(us4*)&embl[v * EMBD]      = u0;
        *(us4*)&embl[v * EMBD + 4]  = u1;
        *(us4*)&embl[v * EMBD + 8]  = u2;
        *(us4*)&embl[v * EMBD + 12] = u3;
    }

    // ---- W fragments / bias / fc_w into registers (no LDS dependency)
    const int nn = lane & 15;   // MFMA col within tile
    const int kg = lane >> 4;   // k-group (k = kg*8+i; k>=16 zero pad)

    frag_ab bfrag[HTPW];
    float   biasr[HTPW], fcwr[HTPW];
    #pragma unroll
    for (int j = 0; j < HTPW; ++j) {
        const int h = wave * (HTPW * 16) + j * 16 + nn;
        biasr[j] = S * (lif_b[h] + beta);
        fcwr[j]  = fc_w[h];
        frag_ab b = {0, 0, 0, 0, 0, 0, 0, 0};
        if (kg < 2) {
            #pragma unroll
            for (int i = 0; i < 8; ++i)
                b[i] = (short)f2b(lif_w[(kg * 8 + i) * HIDD + h]);
        }
        bfrag[j] = b;
    }
    __syncthreads();   // embl ready

    // ---- gather: xw[r][:] = sum_t alpha^(63-t) * emb[xis[r][t]][:]
    // 16 threads/row = 4 t-chunks (c) x 4 e-quads (q). The 4 lanes of a
    // (r,c) group read the SAME xis words (HW broadcast) and consecutive
    // 8B quads of the SAME emb row -> no address divergence, no shuffle.
    {
        const int r = tid >> 4;        // 0..31
        const int c = (tid >> 2) & 3;  // t-chunk (16 t)
        const int q = tid & 3;         // e-quad
        const int4* xp = (const int4*)(xis + (size_t)(row0 + r) * TT + c * 16);
        const int4 iv0 = xp[0], iv1 = xp[1], iv2 = xp[2], iv3 = xp[3];
        const unsigned short* eb = embl + q * 4;
        float ax = 0.f, ay = 0.f, az = 0.f, aw = 0.f;
        float w = 1.f;                 // weight for top t of chunk, *=alpha down
        #define GSTEP(V) { const us4 e = *(const us4*)(eb + ((unsigned)(V) << 4)); \
              ax += w * bf2f(e.x); ay += w * bf2f(e.y); \
              az += w * bf2f(e.z); aw += w * bf2f(e.w); w *= alpha; }
        GSTEP(iv3.w) GSTEP(iv3.z) GSTEP(iv3.y) GSTEP(iv3.x)
        GSTEP(iv2.w) GSTEP(iv2.z) GSTEP(iv2.y) GSTEP(iv2.x)
        GSTEP(iv1.w) GSTEP(iv1.z) GSTEP(iv1.y) GSTEP(iv1.x)
        GSTEP(iv0.w) GSTEP(iv0.z) GSTEP(iv0.y) GSTEP(iv0.x)
        #undef GSTEP
        // chunk c tops out at t=16c+15, global weight alpha^(48-16c)
        const float sc = (c == 3) ? 1.f : ((c == 2) ? a16 : ((c == 1) ? a32 : a48));
        ax *= sc; ay *= sc; az *= sc; aw *= sc;
        // combine 4 chunks (lane bits 2,3)
        ax += __shfl_xor(ax, 4); ay += __shfl_xor(ay, 4);
        az += __shfl_xor(az, 4); aw += __shfl_xor(aw, 4);
        ax += __shfl_xor(ax, 8); ay += __shfl_xor(ay, 8);
        az += __shfl_xor(az, 8); aw += __shfl_xor(aw, 8);
        if (c == 0) {
            us4 u = { f2b(ax), f2b(ay), f2b(az), f2b(aw) };
            *(us4*)&xwb[r * XWPAD + q * 4] = u;
        }
    }
    __syncthreads();   // xwb ready

    // ---- MFMA: 2 row-tiles x 8 h-tiles per wave, fused relu-dot epilogue
    #pragma unroll
    for (int rt = 0; rt < ROWS / 16; ++rt) {
        frag_ab a = {0, 0, 0, 0, 0, 0, 0, 0};
        if (kg < 2)   // real k < 16; kg>=2 lanes stay zero (K padding)
            a = *(const frag_ab*)&xwb[(rt * 16 + nn) * XWPAD + kg * 8];
        frag_cd pacc = {0.f, 0.f, 0.f, 0.f};
        #pragma unroll
        for (int j = 0; j < HTPW; ++j) {
            frag_cd z = { biasr[j], biasr[j], biasr[j], biasr[j] };  // bias as C-in
            frag_cd c = __builtin_amdgcn_mfma_f32_16x16x32_bf16(a, bfrag[j], z, 0, 0, 0);
            #pragma unroll
            for (int x = 0; x < 4; ++x)
                pacc[x] += fmaxf(c[x], 0.f) * fcwr[j];
        }
        #pragma unroll
        for (int m = 1; m <= 8; m <<= 1) {
            #pragma unroll
            for (int x = 0; x < 4; ++x) pacc[x] += __shfl_xor(pacc[x], m);
        }
        if (nn == 0) {
            #pragma unroll
            for (int x = 0; x < 4; ++x)
                red[rt][wave][kg * 4 + x] = pacc[x];   // row m = kg*4+x
        }
    }
    __syncthreads();

    if (tid < ROWS) {
        float s = fc_b[0];
        #pragma unroll
        for (int w2 = 0; w2 < 8; ++w2) s += red[tid >> 4][w2][tid & 15];
        out[row0 + tid] = s;
    }
}

extern "C" void kernel_launch(void* const* d_in, const int* in_sizes, int n_in,
                              void* d_out, int out_size, void* d_ws, size_t ws_size,
                              hipStream_t stream) {
    const int*   xis   = (const int*)d_in[0];
    const float* emb   = (const float*)d_in[1];
    const float* lif_w = (const float*)d_in[2];
    const float* lif_b = (const float*)d_in[3];
    const float* fc_w  = (const float*)d_in[4];
    const float* fc_b  = (const float*)d_in[5];
    const float* alpha = (const float*)d_in[6];
    const float* beta  = (const float*)d_in[7];
    float* out = (float*)d_out;

    ftt_kernel<<<NBLK, NTHR, 0, stream>>>(
        xis, emb, lif_w, lif_b, fc_w, fc_b, alpha, beta, out);
}